// Round 9
// baseline (138.951 us; speedup 1.0000x reference)
//
#include <hip/hip_runtime.h>
#include <math.h>

#define NB 16
#define NN 24
#define NA 384       /* atoms total */
#define FF 128
#define CC 27
#define MAXNBR 32    /* list capacity; physically <= 23 (image spacing L > 2r) */
#define MAXE 24      /* edges used; physical max 23 */
#define MAXEP 34     /* padded LDS rows for s_ge/s_se (pads block LDS > 80KB) */
#define NT 20        /* gauss band terms */
#define NBLK (NA/2)  /* 192 atom-pair blocks */

// ---- static device scratch (d_ws unused). Zero at load; finishers reset their
// batch's flags each call -> clean state per graph replay.
// Sync design (R8, kept): per-atom dataflow flags, plain st_agent stores, NO RMW
// on the sync path, no acquire/release anywhere (R1/R3: agent ACQUIRE = whole-L2
// inv, RELEASE = whole-L2 wb -> storms). Ordering: s_waitcnt vmcnt(0) drains sc
// stores to the LLC (agent coherence point) before the flag store.
// R9: 2 atoms per 1024-thread block -> 195 blocks <= 256 CUs, LDS ~85KB forces
// 1 block/CU: eliminates the 2x-slow doubled-CU blocks that gated every
// dataflow hop in R8 (387 blocks on 256 CUs). P0 is published BEFORE neighbor
// search so search+gauss+preact hide under the first wait window.
__device__ float g_sigma[4];
__device__ float g_projA[NA*4*FF];  // P0, then P2
__device__ float g_projB[NA*4*FF];  // P1
__device__ float g_feat [NA*FF];    // final feats (agent-scope)
__device__ __align__(128) int g_flag[NA][32];    // per-atom phase, own 128-B line
__device__ __align__(128) int g_sigdone[32];     // sigma blocks done (0..3)
__device__ __align__(128) int g_batchdone[32];   // finished batches (0..NB)

__device__ __forceinline__ float softplusf(float x){ return fmaxf(x,0.f) + log1pf(expf(-fabsf(x))); }
__device__ __forceinline__ float sigmoidf(float x){ return 1.f/(1.f+expf(-x)); }
__device__ __forceinline__ void st_agent(float* p, float v){
  __hip_atomic_store(p, v, __ATOMIC_RELAXED, __HIP_MEMORY_SCOPE_AGENT);
}
__device__ __forceinline__ float ld_agent(const float* p){
  return __hip_atomic_load(p, __ATOMIC_RELAXED, __HIP_MEMORY_SCOPE_AGENT);
}
__device__ __forceinline__ void st_agent_i(int* p, int v){
  __hip_atomic_store(p, v, __ATOMIC_RELAXED, __HIP_MEMORY_SCOPE_AGENT);
}
__device__ __forceinline__ int ld_agent_i(const int* p){
  return __hip_atomic_load(p, __ATOMIC_RELAXED, __HIP_MEMORY_SCOPE_AGENT);
}

// Banded Gaussian dot from PRECOMPUTED gauss table (R6-validated, bit-exact).
__device__ __forceinline__ void band_dot2(const float* __restrict__ ga, int kmin,
                                          const float* __restrict__ Wf2,
                                          const float* __restrict__ Ws2, int f,
                                          float& ge, float& se)
{
  float g = 0.f, s = 0.f;
  #pragma unroll
  for (int t = 0; t < NT; t++) {
    float a = ga[t];
    int k = kmin + t;
    g += a * Wf2[k*FF+f];
    s += a * Ws2[k*FF+f];
  }
  ge = g; se = s;
}

// per-quarter GEMV: quarter q computes one of {gi,gj,si,sj} columns
__device__ __forceinline__ float gemv_q(const float* __restrict__ Wf,
                                        const float* __restrict__ Ws,
                                        const float* s_ft, int q, int f)
{
  const float* W = (q==0) ? Wf : (q==1) ? (Wf + FF*FF) : (q==2) ? Ws : (Ws + FF*FF);
  float s = 0.f;
  #pragma unroll 16
  for (int k = 0; k < FF; k++) s += s_ft[k]*W[k*FF+f];
  return s;
}

// drain own stores to LLC, block-wide, then set both atoms' phase flags.
__device__ __forceinline__ void flag_set2(int i0, int v)
{
  asm volatile("s_waitcnt vmcnt(0)" ::: "memory");   // own agent stores at LLC
  __syncthreads();                                    // whole block drained
  if (threadIdx.x == 0) {
    st_agent_i(&g_flag[i0  ][0], v);
    st_agent_i(&g_flag[i0+1][0], v);
  }
}

// wave 0 polls both atoms' neighbor flags (lanes 0-31 atom0, 32-63 atom1);
// satisfied lanes drop out, poll traffic decays.
__device__ __forceinline__ void wait_nbrs2(int n0, int n1,
                                           const int (*s_nj)[MAXNBR], int target)
{
  if (threadIdx.x < 64) {
    int lane = threadIdx.x;
    int jg = -1;
    if (lane < 32) { if (lane < n0)      jg = s_nj[0][lane]; }
    else           { if (lane - 32 < n1) jg = s_nj[1][lane-32]; }
    bool sat = (jg < 0);
    int guard = 0;
    for (;;) {
      if (!sat) sat = (ld_agent_i(&g_flag[jg][0]) >= target);
      if (__all(sat)) break;
      __builtin_amdgcn_s_sleep(4);
      if (++guard > (1<<18)) break;   // fail visibly (absmax) instead of hanging
    }
  }
  __syncthreads();
}

// ====== single fused kernel: 192 atom-pair blocks + 3 sigma blocks ======
// 195 blocks x 1024 thr; ~85KB LDS -> exactly 1 block/CU -> all resident,
// no CU doubling: dataflow spins cannot deadlock, no 2x-slow blocks.
__global__ void __launch_bounds__(1024, 4)
k_fused(const float* __restrict__ pos, const float* __restrict__ cell,
        const float* __restrict__ emb,
        const float* __restrict__ conv_Wf, const float* __restrict__ conv_bf,
        const float* __restrict__ conv_Ws, const float* __restrict__ conv_bs,
        const float* __restrict__ fc_W,  const float* __restrict__ fc_b,
        const float* __restrict__ W_out, const float* __restrict__ b_out,
        const int* __restrict__ z, float* __restrict__ out)
{
  const int tid = threadIdx.x;

  // shared arrays (atom branch; sigma branch reuses sm/s_hh/s_tmp/s_red).
  // total ~85 KB -- deliberately > 80 KB so only ONE block fits per CU.
  __shared__ float s_ft[2][FF];        // running feats (residual state)
  __shared__ float s_cell[9];
  __shared__ float s_rb;
  __shared__ int   s_cnt[2];
  __shared__ int   s_nj[2][MAXNBR];    // neighbor lists (global atom ids)
  __shared__ float s_nd[2][MAXNBR];
  __shared__ float s_nw[2][MAXNBR];
  __shared__ float s_ga[2][MAXE][NT];  // per-edge gauss tables (R6)
  __shared__ int   s_km[2][MAXE];      // per-edge kmin
  __shared__ float s_ge[2][MAXEP][FF]; // preact ge (R7) -- padded rows
  __shared__ float s_se[2][MAXEP][FF]; // preact se (R7) -- padded rows
  __shared__ float s_p[2][4][FF];      // own {gi,gj,si,sj} projections
  __shared__ float sm[2][4][FF];       // msg quarters / GEMV partials
  __shared__ float s_hh[FF], s_tmp[FF], s_red[FF];

  if (blockIdx.x >= NBLK) {
    // ---- spectral-norm power iteration (verbatim R8 math, 512 active thr) ----
    const int m = blockIdx.x - NBLK;
    const int q = (tid >> 7) & 3, f = tid & 127;
    const float* W = fc_W + m*FF*FF;
    if (tid < FF) s_hh[tid] = 0.08838834764831845f;     // u = 1/sqrt(128)
    __syncthreads();
    for (int it = 0; it < 5; it++) {
      if (tid < 512) { float p = 0.f;                   // v = W u (k-split)
        #pragma unroll
        for (int k = q*32; k < q*32+32; k++) p += W[f*FF+k]*s_hh[k];
        sm[0][q][f] = p; }
      __syncthreads();
      if (tid < FF) { float s = sm[0][0][f]+sm[0][1][f]+sm[0][2][f]+sm[0][3][f];
                      s_tmp[f] = s; s_red[f] = s*s; }
      __syncthreads();
      for (int st=64; st>0; st>>=1){ if (tid<st) s_red[tid]+=s_red[tid+st]; __syncthreads(); }
      float nv = sqrtf(s_red[0]) + 1e-12f;
      __syncthreads();
      if (tid < FF) s_tmp[f] /= nv;
      __syncthreads();
      if (tid < 512) { float p = 0.f;                   // u = W^T v (r-split)
        #pragma unroll
        for (int r = q*32; r < q*32+32; r++) p += W[r*FF+f]*s_tmp[r];
        sm[0][q][f] = p; }
      __syncthreads();
      if (tid < FF) { float s = sm[0][0][f]+sm[0][1][f]+sm[0][2][f]+sm[0][3][f];
                      s_hh[f] = s; s_red[f] = s*s; }
      __syncthreads();
      for (int st=64; st>0; st>>=1){ if (tid<st) s_red[tid]+=s_red[tid+st]; __syncthreads(); }
      float nu = sqrtf(s_red[0]) + 1e-12f;
      __syncthreads();
      if (tid < FF) s_hh[f] /= nu;
      __syncthreads();
    }
    if (tid < 512) { float p = 0.f;                     // sigma = v . (W u)
      #pragma unroll
      for (int k = q*32; k < q*32+32; k++) p += W[f*FF+k]*s_hh[k];
      sm[0][q][f] = p; }
    __syncthreads();
    if (tid < FF) s_red[f] = s_tmp[f]*(sm[0][0][f]+sm[0][1][f]+sm[0][2][f]+sm[0][3][f]);
    __syncthreads();
    for (int st=64; st>0; st>>=1){ if (tid<st) s_red[tid]+=s_red[tid+st]; __syncthreads(); }
    if (tid == 0) {
      st_agent(&g_sigma[m], s_red[0]);
      asm volatile("s_waitcnt vmcnt(0)" ::: "memory");
      __hip_atomic_fetch_add(&g_sigdone[0], 1, __ATOMIC_RELAXED, __HIP_MEMORY_SCOPE_AGENT);
    }
    return;
  }

  // ------------- atom-pair block: atoms i0, i0+1 of batch b -------------
  const int i0 = 2*(int)blockIdx.x;
  const int b  = i0 / NN;
  const int a  = tid >> 9;             // which atom half (0/1)
  const int ta = tid & 511;            // thread index within the half
  const int q  = (tid >> 7) & 3;       // quarter within the half
  const int f  = tid & 127;
  const int i  = i0 + a;

  // ---- feat0 + cell (parallel) ----
  if (tid < 2*FF) {
    int aa = tid >> 7, ff = tid & 127;
    int zi = z[i0 + aa]; if (zi < 1) zi = 1; if (zi > 100) zi = 100;
    s_ft[aa][ff] = tanhf(emb[(zi-1)*FF+ff]);
  }
  if (tid >= 512 && tid < 521) s_cell[tid-512] = cell[b*9 + tid - 512];
  if (tid == 1000) { s_cnt[0] = 0; s_cnt[1] = 0; }
  __syncthreads();

  // ---- P0 GEMV + radius (tid0), publish FIRST: search/gauss hide in wait ----
  { float s0 = gemv_q(conv_Wf, conv_Ws, s_ft[a], q, f);
    s_p[a][q][f] = s0;
    st_agent(&g_projA[(i*4+q)*FF+f], s0); }
  if (tid == 0) {
    const float* c = s_cell;
    float cx = c[4]*c[8] - c[5]*c[7];
    float cy = c[5]*c[6] - c[3]*c[8];
    float cz = c[3]*c[7] - c[4]*c[6];
    float vol = c[0]*cx + c[1]*cy + c[2]*cz;
    s_rb = cbrtf(fabsf(vol)/(float)NN);               // RADIUS_RATE = 1
  }
  flag_set2(i0, 1);                    // includes vmcnt drain + __syncthreads

  // ---- neighbor search (each half scans its atom; R8 per-atom pattern) ----
  {
    const float rb = s_rb, rb2 = rb*rb;
    const float pix = pos[i*3+0], piy = pos[i*3+1], piz = pos[i*3+2];
    const float PI = 3.14159265358979323846f;
    for (int cand = ta; cand < NN*CC; cand += 512) {
      int j = cand / CC, c = cand - j*CC;
      float gx = (float)(c/9) - 1.0f;
      float gy = (float)((c/3)%3) - 1.0f;
      float gz = (float)(c%3) - 1.0f;
      float ox = gx*s_cell[0] + gy*s_cell[3] + gz*s_cell[6];
      float oy = gx*s_cell[1] + gy*s_cell[4] + gz*s_cell[7];
      float oz = gx*s_cell[2] + gy*s_cell[5] + gz*s_cell[8];
      int jg = b*NN + j;
      float dx = pix - (pos[jg*3+0] + ox);
      float dy = piy - (pos[jg*3+1] + oy);
      float dz = piz - (pos[jg*3+2] + oz);
      float d2 = dx*dx + dy*dy + dz*dz;
      if (d2 <= rb2 && d2 > 1e-4f) {
        float dist = sqrtf(fmaxf(d2, 1e-4f));
        float w = cosf(dist*PI/rb) + 1.0f;
        int slot = atomicAdd(&s_cnt[a], 1);           // LDS, within the half
        if (slot < MAXNBR) { s_nj[a][slot] = jg; s_nd[a][slot] = dist; s_nw[a][slot] = w; }
      }
    }
  }
  __syncthreads();
  const int nA = (s_cnt[a] > MAXE) ? MAXE : s_cnt[a];  // own atom (phys <= 23)
  const int n0 = (s_cnt[0] > MAXE) ? MAXE : s_cnt[0];
  const int n1 = (s_cnt[1] > MAXE) ? MAXE : s_cnt[1];

  // ---- per-edge gauss tables (expf bits identical to R4's band_dot; R6) ----
  for (int idx = ta; idx < nA*NT; idx += 512) {
    int e = idx / NT, t = idx - e*NT;
    float dist = s_nd[a][e];
    const float step  = 6.0f/127.0f;
    const float coeff = -0.5f/(step*step);
    int kmin = (int)ceilf(dist/step - 9.0f);
    kmin = kmin < 0 ? 0 : (kmin > 108 ? 108 : kmin);
    if (t == 0) s_km[a][e] = kmin;
    int k = kmin + t;
    float dd = dist - step*(float)k;
    s_ga[a][e][t] = expf(coeff*dd*dd);
  }
  __syncthreads();

  // ---- 3 conv layers: preact (hides wait) -> wait(neighbors) -> combine ----
  for (int l = 0; l < 3; ++l) {
    const float* projSrc = (l==1) ? g_projB : g_projA;
    const float* Wf2 = conv_Wf + l*3*FF*FF + 2*FF*FF;
    const float* Ws2 = conv_Ws + l*3*FF*FF + 2*FF*FF;
    // preact: independent of other blocks -> runs while neighbor flags fill.
    for (int idx = ta; idx < nA*FF; idx += 512) {
      int e = idx >> 7, ff = idx & 127;
      float ge, se;
      band_dot2(&s_ga[a][e][0], s_km[a][e], Wf2, Ws2, ff, ge, se);
      s_ge[a][e][ff] = ge; s_se[a][e][ff] = se;
    }
    __syncthreads();
    wait_nbrs2(n0, n1, s_nj, l+1);
    // combine: prefetch the 12 LLC loads back-to-back (one latency exposure),
    // accumulate in the R4-lineage order (quarter q, ascending e).
    {
      const float gi = s_p[a][0][f], si = s_p[a][2][f];
      const float bff = conv_bf[l*FF+f], bsf = conv_bs[l*FF+f];
      float gjv[6], sjv[6];
      #pragma unroll
      for (int t = 0; t < 6; ++t) {
        int e = q + 4*t;
        int jg = (e < nA) ? s_nj[a][e] : 0;      // masked lanes read atom 0 (discarded)
        gjv[t] = ld_agent(&projSrc[(jg*4+1)*FF+f]);
        sjv[t] = ld_agent(&projSrc[(jg*4+3)*FF+f]);
      }
      float msg = 0.f;
      #pragma unroll
      for (int t = 0; t < 6; ++t) {
        int e = q + 4*t;
        if (e < nA)
          msg += sigmoidf(gi + gjv[t] + s_ge[a][e][f] + bff)
               * softplusf(si + sjv[t] + s_se[a][e][f] + bsf) * s_nw[a][e];
      }
      sm[a][q][f] = msg;
    }
    __syncthreads();
    if (tid < 2*FF) {
      int aa = tid >> 7, ff = tid & 127;
      s_ft[aa][ff] = softplusf(s_ft[aa][ff] + sm[aa][0][ff] + sm[aa][1][ff]
                                            + sm[aa][2][ff] + sm[aa][3][ff]);
    }
    __syncthreads();
    if (l < 2) {
      const float* WfN = conv_Wf + (l+1)*3*FF*FF;
      const float* WsN = conv_Ws + (l+1)*3*FF*FF;
      float* projDst = (l==0) ? g_projB : g_projA;  // P2 over P0: safe -- readers
      float s1 = gemv_q(WfN, WsN, s_ft[a], q, f);   // of P0[i]=N(i) all have flag>=2
      s_p[a][q][f] = s1;
      st_agent(&projDst[(i*4+q)*FF+f], s1);
      flag_set2(i0, l+2);
    }
  }

  // ---- final feats ----
  if (tid < 2*FF) {
    int aa = tid >> 7, ff = tid & 127;
    st_agent(&g_feat[(i0+aa)*FF+ff], s_ft[aa][ff]);
  }
  flag_set2(i0, 4);
  if (i0 != b*NN) return;                      // only the designated finisher stays

  // ---------- designated finisher of batch b: mean + FC chain + head ----------
  if (tid < 64) {                              // wait all 24 batch flags >= 4
    int jg = (tid < NN) ? (b*NN + tid) : -1;
    bool sat = (jg < 0);
    int guard = 0;
    for (;;) {
      if (!sat) sat = (ld_agent_i(&g_flag[jg][0]) >= 4);
      if (__all(sat)) break;
      __builtin_amdgcn_s_sleep(4);
      if (++guard > (1<<18)) break;
    }
  }
  __syncthreads();
  if (tid < NN) st_agent_i(&g_flag[b*NN+tid][0], 0);   // reset batch flags (replay)
  if (tid == 0) {                              // sigma must be published
    int guard = 0;
    while (__hip_atomic_load(&g_sigdone[0], __ATOMIC_RELAXED, __HIP_MEMORY_SCOPE_AGENT) < 3) {
      __builtin_amdgcn_s_sleep(4);
      if (++guard > (1<<18)) break;
    }
  }
  __syncthreads();
  if (tid < FF) {
    float s0 = 0.f;
    for (int aa = 0; aa < NN; aa++) s0 += ld_agent(&g_feat[(b*NN+aa)*FF+tid]);
    s_hh[tid] = s0/(float)NN;
  }
  __syncthreads();
  for (int l = 0; l < 3; l++) {
    if (tid < 512) { float p = 0.f;
      #pragma unroll
      for (int k = q*32; k < q*32+32; k++) p += s_hh[k]*fc_W[l*FF*FF + k*FF + f];
      sm[0][q][f] = p; }
    __syncthreads();
    if (tid < FF) {
      float s = sm[0][0][tid]+sm[0][1][tid]+sm[0][2][tid]+sm[0][3][tid];
      s_tmp[tid] = softplusf(s/ld_agent(&g_sigma[l]) + fc_b[l*FF+tid]);
    }
    __syncthreads();
    if (tid < FF) s_hh[tid] = s_tmp[tid];
    __syncthreads();
  }
  if (tid < FF) s_red[tid] = s_hh[tid]*W_out[tid];
  __syncthreads();
  if (tid < 64) {
    float t = s_red[tid] + s_red[tid+64];
    #pragma unroll
    for (int off = 32; off > 0; off >>= 1) t += __shfl_xor(t, off);
    if (tid == 0) {
      out[b] = t + b_out[0];
      int d = __hip_atomic_fetch_add(&g_batchdone[0], 1, __ATOMIC_RELAXED,
                                     __HIP_MEMORY_SCOPE_AGENT);
      if (d == NB-1) {                         // globally last finisher
        __hip_atomic_store(&g_batchdone[0], 0, __ATOMIC_RELAXED, __HIP_MEMORY_SCOPE_AGENT);
        __hip_atomic_store(&g_sigdone[0],   0, __ATOMIC_RELAXED, __HIP_MEMORY_SCOPE_AGENT);
      }
    }
  }
}

extern "C" void kernel_launch(void* const* d_in, const int* in_sizes, int n_in,
                              void* d_out, int out_size, void* d_ws, size_t ws_size,
                              hipStream_t stream) {
  const float* pos     = (const float*)d_in[0];
  const float* cell    = (const float*)d_in[1];
  const float* emb     = (const float*)d_in[2];
  const float* conv_Wf = (const float*)d_in[3];
  const float* conv_bf = (const float*)d_in[4];
  const float* conv_Ws = (const float*)d_in[5];
  const float* conv_bs = (const float*)d_in[6];
  const float* fc_W    = (const float*)d_in[7];
  const float* fc_b    = (const float*)d_in[8];
  const float* W_out   = (const float*)d_in[9];
  const float* b_out   = (const float*)d_in[10];
  const int*   z       = (const int*)d_in[11];
  // d_in[12] = batch (unused); d_ws unused. All tensors fp32 (validated R3-R14).

  k_fused<<<NBLK+3, 1024, 0, stream>>>(pos, cell, emb, conv_Wf, conv_bf,
                                       conv_Ws, conv_bs, fc_W, fc_b,
                                       W_out, b_out, z, (float*)d_out);
}